// Round 1
// baseline (230.414 us; speedup 1.0000x reference)
//
#include <hip/hip_runtime.h>

constexpr int Bn = 8, Tn = 4096, Dn = 512, Hn = 512;
constexpr int Mn = Bn * Tn;          // 32768 rows
constexpr int BM = 128, BHt = 128, BK = 32;
constexpr int CH = 64, NC = Tn / CH; // scan chunking

typedef __attribute__((ext_vector_type(8))) short s8v;   // 8 bf16 (4 VGPRs)
typedef __attribute__((ext_vector_type(4))) float f4v;   // MFMA acc

__device__ __forceinline__ short f2bf(float f) {
  unsigned u = __float_as_uint(f);
  u = (u + 0x7fffu + ((u >> 16) & 1u)) >> 16;   // RNE
  return (short)u;
}

// Stage a 128-row x 32-k fp32 tile as bf16 into LDS in MFMA-fragment order:
// chunk index = (r>>4)*64 + (k8)*16 + (r&15), 16B per chunk -> conflict-free
// ds_write_b128 (64 consecutive chunks per wave) and conflict-free ds_read_b128.
__device__ __forceinline__ void stage_tile(const float* __restrict__ src,
                                           int row0, int k0, short* lds, int tid) {
#pragma unroll
  for (int p = 0; p < 2; p++) {
    int idx = tid + p * 256;
    int r = idx >> 2, kk8 = idx & 3;
    const float4* sv = reinterpret_cast<const float4*>(
        src + (size_t)(row0 + r) * Dn + k0 + kk8 * 8);
    float4 f0 = sv[0], f1 = sv[1];
    s8v v;
    v[0] = f2bf(f0.x); v[1] = f2bf(f0.y); v[2] = f2bf(f0.z); v[3] = f2bf(f0.w);
    v[4] = f2bf(f1.x); v[5] = f2bf(f1.y); v[6] = f2bf(f1.z); v[7] = f2bf(f1.w);
    *reinterpret_cast<s8v*>(&lds[(size_t)((r >> 4) * 64 + kk8 * 16 + (r & 15)) * 8]) = v;
  }
}

// Fused dual-GEMM + activations: cf = 1 - sigmoid(XWz^T + bz), ad = sigmoid*tanh(XWh^T + bh)
__global__ __launch_bounds__(256) void gemm_act(
    const float* __restrict__ X,
    const float* __restrict__ Wz, const float* __restrict__ bz,
    const float* __restrict__ Wh, const float* __restrict__ bh,
    float* __restrict__ cf, float* __restrict__ ad) {
  __shared__ __align__(16) short lX[BM / 16 * 64 * 8];
  __shared__ __align__(16) short lWz[BHt / 16 * 64 * 8];
  __shared__ __align__(16) short lWh[BHt / 16 * 64 * 8];

  int tid = threadIdx.x;
  int lane = tid & 63, wid = tid >> 6;
  int wr = wid >> 1, wc = wid & 1;           // 2x2 waves, each 64x64 per matrix
  int m0 = blockIdx.x * BM, h0 = blockIdx.y * BHt;

  f4v accz[4][4], acch[4][4];
#pragma unroll
  for (int i = 0; i < 4; i++)
#pragma unroll
    for (int j = 0; j < 4; j++) {
      accz[i][j] = (f4v){0.f, 0.f, 0.f, 0.f};
      acch[i][j] = (f4v){0.f, 0.f, 0.f, 0.f};
    }

  for (int ks = 0; ks < Dn / BK; ks++) {
    int k0 = ks * BK;
    __syncthreads();
    stage_tile(X, m0, k0, lX, tid);
    stage_tile(Wz, h0, k0, lWz, tid);
    stage_tile(Wh, h0, k0, lWh, tid);
    __syncthreads();

    s8v af[4], bzf[4], bhf[4];
#pragma unroll
    for (int i = 0; i < 4; i++)
      af[i] = *reinterpret_cast<s8v*>(&lX[((wr * 4 + i) * 64 + lane) * 8]);
#pragma unroll
    for (int j = 0; j < 4; j++) {
      bzf[j] = *reinterpret_cast<s8v*>(&lWz[((wc * 4 + j) * 64 + lane) * 8]);
      bhf[j] = *reinterpret_cast<s8v*>(&lWh[((wc * 4 + j) * 64 + lane) * 8]);
    }
#pragma unroll
    for (int i = 0; i < 4; i++)
#pragma unroll
      for (int j = 0; j < 4; j++) {
        accz[i][j] = __builtin_amdgcn_mfma_f32_16x16x32_bf16(af[i], bzf[j], accz[i][j], 0, 0, 0);
        acch[i][j] = __builtin_amdgcn_mfma_f32_16x16x32_bf16(af[i], bhf[j], acch[i][j], 0, 0, 0);
      }
  }

  // epilogue: C/D layout col=lane&15, row=(lane>>4)*4+q  [measured m89/m91]
#pragma unroll
  for (int i = 0; i < 4; i++)
#pragma unroll
    for (int j = 0; j < 4; j++) {
#pragma unroll
      for (int q = 0; q < 4; q++) {
        int m = m0 + wr * 64 + i * 16 + (lane >> 4) * 4 + q;
        int h = h0 + wc * 64 + j * 16 + (lane & 15);
        float vz = accz[i][j][q] + bz[h];
        float z = 1.f / (1.f + __expf(-vz));
        float vh = acch[i][j][q] + bh[h];
        float e = __expf(2.f * vh);
        float th = 1.f - 2.f / (e + 1.f);   // tanh, saturates cleanly at +-1
        size_t off = (size_t)m * Hn + h;
        cf[off] = 1.f - z;
        ad[off] = z * th;
      }
    }
}

// S1: per (chunk, b, h) compose the 64-step affine transform -> (A, B)
__global__ __launch_bounds__(256) void scan_chunk(
    const float* __restrict__ cf, const float* __restrict__ ad,
    float* __restrict__ cA, float* __restrict__ cB) {
  int h = blockIdx.y * 256 + threadIdx.x;
  int c = blockIdx.x, b = blockIdx.z;
  size_t base = ((size_t)b * Tn + (size_t)c * CH) * Hn + h;
  float A = 1.f, Bc = 0.f;
#pragma unroll 8
  for (int t = 0; t < CH; t++) {
    float a = cf[base + (size_t)t * Hn];
    float bb = ad[base + (size_t)t * Hn];
    Bc = fmaf(a, Bc, bb);
    A *= a;
  }
  size_t o = (size_t)(b * NC + c) * Hn + h;
  cA[o] = A;
  cB[o] = Bc;
}

// S2: serial scan over the 64 chunk summaries -> h_start per chunk
__global__ __launch_bounds__(256) void scan_heads(
    const float* __restrict__ cA, const float* __restrict__ cB,
    const float* __restrict__ h0p, float* __restrict__ hst) {
  int b = blockIdx.x >> 1;
  int h = (blockIdx.x & 1) * 256 + threadIdx.x;
  float hr = h0p[(size_t)b * Hn + h];
#pragma unroll 8
  for (int c = 0; c < NC; c++) {
    size_t o = (size_t)(b * NC + c) * Hn + h;
    hst[o] = hr;
    hr = fmaf(cA[o], hr, cB[o]);
  }
}

// S3: replay each chunk from its h_start, writing outputs
__global__ __launch_bounds__(256) void scan_apply(
    const float* __restrict__ cf, const float* __restrict__ ad,
    const float* __restrict__ hst, float* __restrict__ out) {
  int h = blockIdx.y * 256 + threadIdx.x;
  int c = blockIdx.x, b = blockIdx.z;
  float hr = hst[(size_t)(b * NC + c) * Hn + h];
  size_t base = ((size_t)b * Tn + (size_t)c * CH) * Hn + h;
#pragma unroll 4
  for (int t = 0; t < CH; t++) {
    float a = cf[base + (size_t)t * Hn];
    float bb = ad[base + (size_t)t * Hn];
    hr = fmaf(a, hr, bb);
    out[base + (size_t)t * Hn] = hr;
  }
}

extern "C" void kernel_launch(void* const* d_in, const int* in_sizes, int n_in,
                              void* d_out, int out_size, void* d_ws, size_t ws_size,
                              hipStream_t stream) {
  const float* X   = (const float*)d_in[0];
  const float* h0p = (const float*)d_in[1];
  const float* Wz  = (const float*)d_in[2];
  const float* bz  = (const float*)d_in[3];
  const float* Wh  = (const float*)d_in[4];
  const float* bh  = (const float*)d_in[5];
  float* out = (float*)d_out;

  char* ws = (char*)d_ws;
  size_t mat = (size_t)Mn * Hn * 4;            // 67.1 MB each
  float* cf = (float*)ws;
  float* ad = (float*)(ws + mat);
  float* cA = (float*)(ws + 2 * mat);
  float* cB = cA + (size_t)Bn * NC * Hn;
  float* hst = cB + (size_t)Bn * NC * Hn;

  dim3 g1(Mn / BM, Hn / BHt, 1);               // 256 x 4 blocks
  gemm_act<<<g1, 256, 0, stream>>>(X, Wz, bz, Wh, bh, cf, ad);

  dim3 g2(NC, Hn / 256, Bn);                   // 64 x 2 x 8 blocks
  scan_chunk<<<g2, 256, 0, stream>>>(cf, ad, cA, cB);
  scan_heads<<<dim3(Bn * Hn / 256), 256, 0, stream>>>(cA, cB, h0p, hst);
  scan_apply<<<g2, 256, 0, stream>>>(cf, ad, hst, out);
}

// Round 3
// 143.427 us; speedup vs baseline: 1.6065x; 1.6065x over previous
//
#include <hip/hip_runtime.h>

constexpr int Bn = 8, Tn = 4096, Dn = 512, Hn = 512;
constexpr int Mn = Bn * Tn;            // 32768 rows
constexpr int BM = 128, BHt = 128, BK = 32;
constexpr int NKT = Dn / BK;           // 16 k-tiles
constexpr int CH = 64, NC = Tn / CH;   // 64 chunks of 64 steps

typedef __attribute__((ext_vector_type(8))) short s8v;       // 8 bf16
typedef __attribute__((ext_vector_type(4))) float f4v;       // MFMA acc
typedef __attribute__((ext_vector_type(8))) _Float16 h8v;    // 16B granule: a[0..3], b[0..3]
typedef unsigned short ushort_t;

typedef __attribute__((address_space(1))) const void gv_t;   // global src for load_lds
typedef __attribute__((address_space(3))) void lv_t;         // LDS dst for load_lds

__device__ __forceinline__ short f2bf(float f) {
  unsigned u = __float_as_uint(f);
  u = (u + 0x7fffu + ((u >> 16) & 1u)) >> 16;   // RNE
  return (short)u;
}

// fp32 [rows][512] -> bf16 tiles of 128 rows x 32 k in MFMA-fragment order.
// Tile bx = rt*16 + kt; within tile, 16B chunk c = (r>>4)*64 + k8*16 + (r&15)
// holds row r's elements [k8*8 .. +8]. Linear LDS load of this block IS the
// fragment layout the GEMM's ds_read_b128 expects (conflict-free both sides).
__global__ __launch_bounds__(256) void convert_tile(
    const float* __restrict__ src, ushort_t* __restrict__ dst) {
  int bx = blockIdx.x, tid = threadIdx.x;
  const float* tsrc = src + ((size_t)(bx >> 4) * 128) * Dn + (bx & 15) * BK;
#pragma unroll
  for (int p = 0; p < 2; p++) {
    int idx = tid + p * 256;
    int r = idx >> 2, k8 = idx & 3;
    const float4* sv = reinterpret_cast<const float4*>(tsrc + (size_t)r * Dn + k8 * 8);
    float4 f0 = sv[0], f1 = sv[1];
    s8v v;
    v[0] = f2bf(f0.x); v[1] = f2bf(f0.y); v[2] = f2bf(f0.z); v[3] = f2bf(f0.w);
    v[4] = f2bf(f1.x); v[5] = f2bf(f1.y); v[6] = f2bf(f1.z); v[7] = f2bf(f1.w);
    int c = (r >> 4) * 64 + k8 * 16 + (r & 15);
    *reinterpret_cast<s8v*>(&dst[((size_t)bx * 512 + c) * 8]) = v;
  }
}

// Dual bf16 GEMM (shared X tile) + activation epilogue.
// Output: packed fp16 granules, wave-tile layout:
//   wave tile = 64 t x 64 h; granule chunk = (R*8+Cc)*1024 + (i*4+j)*64 + lane,
//   holding {a(q=0..3), b(q=0..3)} for t_loc = i*16 + (lane>>4)*4 + q,
//   h_loc = j*16 + (lane&15).  R = m/64, Cc = h/64.
__global__ __launch_bounds__(256) void gemm_act(
    const ushort_t* __restrict__ Xb, const ushort_t* __restrict__ Wzb,
    const ushort_t* __restrict__ Whb,
    const float* __restrict__ bzp, const float* __restrict__ bhp,
    h8v* __restrict__ cab) {
  __shared__ __align__(16) ushort_t lds[3 * 4096];   // 24 KB
  ushort_t* lX = lds;
  ushort_t* lWz = lds + 4096;
  ushort_t* lWh = lds + 8192;

  int tid = threadIdx.x, lane = tid & 63, wid = tid >> 6;
  int wr = wid >> 1, wc = wid & 1;             // 2x2 waves, 64x64 each
  int bm = blockIdx.x, bhb = blockIdx.y;

  f4v accz[4][4], acch[4][4];
#pragma unroll
  for (int i = 0; i < 4; i++)
#pragma unroll
    for (int j = 0; j < 4; j++) {
      accz[i][j] = (f4v){0.f, 0.f, 0.f, 0.f};
      acch[i][j] = (f4v){0.f, 0.f, 0.f, 0.f};
    }

  for (int ks = 0; ks < NKT; ks++) {
    const ushort_t* xs = Xb + (size_t)(bm * NKT + ks) * 4096;
    const ushort_t* zs = Wzb + (size_t)(bhb * NKT + ks) * 4096;
    const ushort_t* hs = Whb + (size_t)(bhb * NKT + ks) * 4096;
    __syncthreads();
#pragma unroll
    for (int p = 0; p < 2; p++) {
      int off = p * 2048 + tid * 8;
      __builtin_amdgcn_global_load_lds((gv_t*)(xs + off), (lv_t*)(lX + off), 16, 0, 0);
      __builtin_amdgcn_global_load_lds((gv_t*)(zs + off), (lv_t*)(lWz + off), 16, 0, 0);
      __builtin_amdgcn_global_load_lds((gv_t*)(hs + off), (lv_t*)(lWh + off), 16, 0, 0);
    }
    __syncthreads();

    s8v af[4], bzf[4], bhf[4];
#pragma unroll
    for (int i = 0; i < 4; i++)
      af[i] = *reinterpret_cast<s8v*>(&lX[((wr * 4 + i) * 64 + lane) * 8]);
#pragma unroll
    for (int j = 0; j < 4; j++) {
      bzf[j] = *reinterpret_cast<s8v*>(&lWz[((wc * 4 + j) * 64 + lane) * 8]);
      bhf[j] = *reinterpret_cast<s8v*>(&lWh[((wc * 4 + j) * 64 + lane) * 8]);
    }
#pragma unroll
    for (int i = 0; i < 4; i++)
#pragma unroll
      for (int j = 0; j < 4; j++) {
        accz[i][j] = __builtin_amdgcn_mfma_f32_16x16x32_bf16(af[i], bzf[j], accz[i][j], 0, 0, 0);
        acch[i][j] = __builtin_amdgcn_mfma_f32_16x16x32_bf16(af[i], bhf[j], acch[i][j], 0, 0, 0);
      }
  }

  // epilogue: C/D layout col=lane&15, row=(lane>>4)*4+q  [m89/m91]
  int R = bm * 2 + wr, Cc = bhb * 2 + wc;
  size_t base = (size_t)(R * 8 + Cc) * 1024;
  float bzv[4], bhv[4];
#pragma unroll
  for (int j = 0; j < 4; j++) {
    int h = bhb * BHt + wc * 64 + j * 16 + (lane & 15);
    bzv[j] = bzp[h];
    bhv[j] = bhp[h];
  }
#pragma unroll
  for (int i = 0; i < 4; i++)
#pragma unroll
    for (int j = 0; j < 4; j++) {
      h8v g;
#pragma unroll
      for (int q = 0; q < 4; q++) {
        float z = 1.f / (1.f + __expf(-(accz[i][j][q] + bzv[j])));
        float e = __expf(2.f * (acch[i][j][q] + bhv[j]));
        float th = 1.f - 2.f / (e + 1.f);
        g[q] = (_Float16)(1.f - z);        // a_t
        g[4 + q] = (_Float16)(z * th);     // b_t
      }
      cab[base + (size_t)((i * 4 + j) * 64 + lane)] = g;
    }
}

// S1: per (R = b*64+c, h) compose the 64-step affine transform -> (A, B)
__global__ __launch_bounds__(256) void scan_chunk(
    const h8v* __restrict__ cab, float* __restrict__ cA, float* __restrict__ cB) {
  int h = blockIdx.y * 256 + threadIdx.x;
  int R = blockIdx.x;
  int hl = h & 63, Cc = h >> 6;
  size_t base = (size_t)(R * 8 + Cc) * 1024 + (size_t)(hl >> 4) * 64 + (hl & 15);
  float A = 1.f, Bv = 0.f;
#pragma unroll
  for (int i = 0; i < 4; i++)
#pragma unroll
    for (int p = 0; p < 4; p++) {
      h8v g = cab[base + i * 256 + p * 16];
#pragma unroll
      for (int q = 0; q < 4; q++) {
        float a = (float)g[q], b = (float)g[4 + q];
        A *= a;
        Bv = fmaf(a, Bv, b);
      }
    }
  cA[(size_t)R * Hn + h] = A;
  cB[(size_t)R * Hn + h] = Bv;
}

// S2: serial scan over 64 chunk summaries per (b,h) -> h_start per chunk
__global__ __launch_bounds__(256) void scan_heads(
    const float* __restrict__ cA, const float* __restrict__ cB,
    const float* __restrict__ h0p, float* __restrict__ hst) {
  int gid = blockIdx.x * 256 + threadIdx.x;   // 4096 = B*H
  int b = gid >> 9, h = gid & 511;
  float hr = h0p[(size_t)b * Hn + h];
#pragma unroll 8
  for (int c = 0; c < NC; c++) {
    size_t o = (size_t)(b * NC + c) * Hn + h;
    hst[o] = hr;
    hr = fmaf(cA[o], hr, cB[o]);
  }
}

// S3: replay each chunk from its h_start, write fp32 outputs (B,T,H)
__global__ __launch_bounds__(256) void scan_apply(
    const h8v* __restrict__ cab, const float* __restrict__ hst,
    float* __restrict__ out) {
  int h = blockIdx.y * 256 + threadIdx.x;
  int R = blockIdx.x;
  int hl = h & 63, Cc = h >> 6;
  size_t base = (size_t)(R * 8 + Cc) * 1024 + (size_t)(hl >> 4) * 64 + (hl & 15);
  float hr = hst[(size_t)R * Hn + h];
  size_t ob = (size_t)R * 64 * Hn + h;
#pragma unroll
  for (int i = 0; i < 4; i++)
#pragma unroll
    for (int p = 0; p < 4; p++) {
      h8v g = cab[base + i * 256 + p * 16];
#pragma unroll
      for (int q = 0; q < 4; q++) {
        hr = fmaf((float)g[q], hr, (float)g[4 + q]);
        out[ob + (size_t)(i * 16 + p * 4 + q) * Hn] = hr;
      }
    }
}

extern "C" void kernel_launch(void* const* d_in, const int* in_sizes, int n_in,
                              void* d_out, int out_size, void* d_ws, size_t ws_size,
                              hipStream_t stream) {
  const float* X   = (const float*)d_in[0];
  const float* h0p = (const float*)d_in[1];
  const float* Wz  = (const float*)d_in[2];
  const float* bz  = (const float*)d_in[3];
  const float* Wh  = (const float*)d_in[4];
  const float* bh  = (const float*)d_in[5];
  float* out = (float*)d_out;

  char* ws = (char*)d_ws;
  ushort_t* Xb  = (ushort_t*)ws;                                  // 33.6 MB
  ushort_t* Wzb = Xb + (size_t)Mn * Dn;                           // 0.5 MB
  ushort_t* Whb = Wzb + (size_t)Hn * Dn;                          // 0.5 MB
  h8v* cab      = (h8v*)(Whb + (size_t)Hn * Dn);                  // 67.1 MB
  // cab = Mn*Hn elements x (a,b) = 2*Mn*Hn halves = Mn*Hn/4 granules (16B each)
  float* cA     = (float*)(cab + (size_t)Mn * Hn / 4);            // 1 MB  [round-2 bug: was /8 -> aliased cab]
  float* cB     = cA + (size_t)Bn * NC * Hn;                      // 1 MB
  float* hst    = cB + (size_t)Bn * NC * Hn;                      // 1 MB

  convert_tile<<<dim3((Mn / 128) * NKT), 256, 0, stream>>>(X, Xb);
  convert_tile<<<dim3((Hn / 128) * NKT), 256, 0, stream>>>(Wz, Wzb);
  convert_tile<<<dim3((Hn / 128) * NKT), 256, 0, stream>>>(Wh, Whb);

  gemm_act<<<dim3(Mn / BM, Hn / BHt), 256, 0, stream>>>(Xb, Wzb, Whb, bz, bh, cab);

  scan_chunk<<<dim3(Mn / 64, Hn / 256), 256, 0, stream>>>(cab, cA, cB);
  scan_heads<<<dim3(Bn * Hn / 256), 256, 0, stream>>>(cA, cB, h0p, hst);
  scan_apply<<<dim3(Mn / 64, Hn / 256), 256, 0, stream>>>(cab, hst, out);
}

// Round 4
// 111.263 us; speedup vs baseline: 2.0709x; 1.2891x over previous
//
#include <hip/hip_runtime.h>

constexpr int Bn = 8, Tn = 4096, Dn = 512, Hn = 512;
constexpr int Mn = Bn * Tn;            // 32768 rows
constexpr int BM = 128, BHt = 128, BK = 32;
constexpr int NKT = Dn / BK;           // 16 k-tiles
constexpr int CH = 64, NC = Tn / CH;   // 64 chunks of 64 steps

typedef __attribute__((ext_vector_type(8))) short s8v;       // 8 bf16
typedef __attribute__((ext_vector_type(4))) float f4v;       // MFMA acc
typedef __attribute__((ext_vector_type(8))) _Float16 h8v;    // 16B granule: a[0..3], b[0..3]
typedef unsigned short ushort_t;

typedef __attribute__((address_space(1))) const void gv_t;   // global src for load_lds
typedef __attribute__((address_space(3))) void lv_t;         // LDS dst for load_lds

__device__ __forceinline__ short f2bf(float f) {
  unsigned u = __float_as_uint(f);
  u = (u + 0x7fffu + ((u >> 16) & 1u)) >> 16;   // RNE
  return (short)u;
}

// fp32 [rows][512] -> bf16 tiles of 128 rows x 32 k in MFMA-fragment order.
// Tile t = rt*16 + kt; within tile, 16B chunk c = (r>>4)*64 + k8*16 + (r&15)
// holds row r's elements [k8*8 .. +8]. Linear LDS image of this block IS the
// fragment layout the GEMM's ds_read_b128 expects (conflict-free both sides).
// One merged kernel: blocks [0,4096) = X, [4096,4160) = Wz, [4160,4224) = Wh.
__global__ __launch_bounds__(256) void convert_all(
    const float* __restrict__ X, const float* __restrict__ Wz,
    const float* __restrict__ Wh, ushort_t* __restrict__ Xb,
    ushort_t* __restrict__ Wzb, ushort_t* __restrict__ Whb) {
  int bx = blockIdx.x, tid = threadIdx.x;
  const float* src;
  ushort_t* dst;
  int lb;
  if (bx < 4096)      { src = X;  dst = Xb;  lb = bx; }
  else if (bx < 4160) { src = Wz; dst = Wzb; lb = bx - 4096; }
  else                { src = Wh; dst = Whb; lb = bx - 4160; }
  const float* tsrc = src + ((size_t)(lb >> 4) * 128) * Dn + (lb & 15) * BK;
#pragma unroll
  for (int p = 0; p < 2; p++) {
    int idx = tid + p * 256;
    int r = idx >> 2, k8 = idx & 3;
    const float4* sv = reinterpret_cast<const float4*>(tsrc + (size_t)r * Dn + k8 * 8);
    float4 f0 = sv[0], f1 = sv[1];
    s8v v;
    v[0] = f2bf(f0.x); v[1] = f2bf(f0.y); v[2] = f2bf(f0.z); v[3] = f2bf(f0.w);
    v[4] = f2bf(f1.x); v[5] = f2bf(f1.y); v[6] = f2bf(f1.z); v[7] = f2bf(f1.w);
    int c = (r >> 4) * 64 + k8 * 16 + (r & 15);
    *reinterpret_cast<s8v*>(&dst[((size_t)lb * 512 + c) * 8]) = v;
  }
}

// Dual bf16 GEMM (shared X tile) + activation epilogue.
// Double-buffered LDS, prefetch next K-tile, counted vmcnt(6), raw s_barrier.
// Output: packed fp16 granules, wave-tile layout:
//   granule chunk = (R*8+Cc)*1024 + (i*4+j)*64 + lane holding {a,b} for
//   t_loc = i*16 + (lane>>4)*4 + q, h_loc = j*16 + (lane&15); R=m/64, Cc=h/64.
__global__ __launch_bounds__(256) void gemm_act(
    const ushort_t* __restrict__ Xb, const ushort_t* __restrict__ Wzb,
    const ushort_t* __restrict__ Whb,
    const float* __restrict__ bzp, const float* __restrict__ bhp,
    h8v* __restrict__ cab) {
  __shared__ __align__(16) ushort_t lds[2][3 * 4096];   // 48 KB double buffer

  int tid = threadIdx.x, lane = tid & 63, wid = tid >> 6;
  int wr = wid >> 1, wc = wid & 1;             // 2x2 waves, 64x64 each
  int bm = blockIdx.x, bhb = blockIdx.y;

  const ushort_t* xs = Xb + (size_t)bm * NKT * 4096;
  const ushort_t* zs = Wzb + (size_t)bhb * NKT * 4096;
  const ushort_t* hs = Whb + (size_t)bhb * NKT * 4096;

  f4v accz[4][4], acch[4][4];
#pragma unroll
  for (int i = 0; i < 4; i++)
#pragma unroll
    for (int j = 0; j < 4; j++) {
      accz[i][j] = (f4v){0.f, 0.f, 0.f, 0.f};
      acch[i][j] = (f4v){0.f, 0.f, 0.f, 0.f};
    }

  auto stage = [&](int buf, int ks) {
    ushort_t* l = lds[buf];
#pragma unroll
    for (int p = 0; p < 2; p++) {
      int off = p * 2048 + tid * 8;
      size_t go = (size_t)ks * 4096 + off;
      __builtin_amdgcn_global_load_lds((gv_t*)(xs + go), (lv_t*)(l + off), 16, 0, 0);
      __builtin_amdgcn_global_load_lds((gv_t*)(zs + go), (lv_t*)(l + 4096 + off), 16, 0, 0);
      __builtin_amdgcn_global_load_lds((gv_t*)(hs + go), (lv_t*)(l + 8192 + off), 16, 0, 0);
    }
  };

  stage(0, 0);
  for (int ks = 0; ks < NKT; ks++) {
    int cur = ks & 1;
    if (ks + 1 < NKT) {
      stage(cur ^ 1, ks + 1);                          // 6 loads in flight for next
      asm volatile("s_waitcnt vmcnt(6)" ::: "memory"); // current tile's 6 landed
    } else {
      asm volatile("s_waitcnt vmcnt(0)" ::: "memory");
    }
    __builtin_amdgcn_sched_barrier(0);
    __builtin_amdgcn_s_barrier();                      // all waves: cur LDS ready
    __builtin_amdgcn_sched_barrier(0);

    ushort_t* l = lds[cur];
    s8v af[4], bzf[4], bhf[4];
#pragma unroll
    for (int i = 0; i < 4; i++)
      af[i] = *reinterpret_cast<s8v*>(&l[((wr * 4 + i) * 64 + lane) * 8]);
#pragma unroll
    for (int j = 0; j < 4; j++) {
      bzf[j] = *reinterpret_cast<s8v*>(&l[4096 + ((wc * 4 + j) * 64 + lane) * 8]);
      bhf[j] = *reinterpret_cast<s8v*>(&l[8192 + ((wc * 4 + j) * 64 + lane) * 8]);
    }
#pragma unroll
    for (int i = 0; i < 4; i++)
#pragma unroll
      for (int j = 0; j < 4; j++) {
        accz[i][j] = __builtin_amdgcn_mfma_f32_16x16x32_bf16(af[i], bzf[j], accz[i][j], 0, 0, 0);
        acch[i][j] = __builtin_amdgcn_mfma_f32_16x16x32_bf16(af[i], bhf[j], acch[i][j], 0, 0, 0);
      }
    __builtin_amdgcn_sched_barrier(0);
    __builtin_amdgcn_s_barrier();                      // cur free for overwrite
  }

  // epilogue: C/D layout col=lane&15, row=(lane>>4)*4+q  [m89/m91]
  int R = bm * 2 + wr, Cc = bhb * 2 + wc;
  size_t base = (size_t)(R * 8 + Cc) * 1024;
  float bzv[4], bhv[4];
#pragma unroll
  for (int j = 0; j < 4; j++) {
    int h = bhb * BHt + wc * 64 + j * 16 + (lane & 15);
    bzv[j] = bzp[h];
    bhv[j] = bhp[h];
  }
#pragma unroll
  for (int i = 0; i < 4; i++)
#pragma unroll
    for (int j = 0; j < 4; j++) {
      h8v g;
#pragma unroll
      for (int q = 0; q < 4; q++) {
        float z = 1.f / (1.f + __expf(-(accz[i][j][q] + bzv[j])));
        float e = __expf(2.f * (acch[i][j][q] + bhv[j]));
        float th = 1.f - 2.f / (e + 1.f);
        g[q] = (_Float16)(1.f - z);        // a_t
        g[4 + q] = (_Float16)(z * th);     // b_t
      }
      cab[base + (size_t)((i * 4 + j) * 64 + lane)] = g;
    }
}

// S1: per (R = b*64+c, h) compose the 64-step affine transform -> (A, B)
__global__ __launch_bounds__(256) void scan_chunk(
    const h8v* __restrict__ cab, float* __restrict__ cA, float* __restrict__ cB) {
  int h = blockIdx.y * 256 + threadIdx.x;
  int R = blockIdx.x;
  int hl = h & 63, Cc = h >> 6;
  size_t base = (size_t)(R * 8 + Cc) * 1024 + (size_t)(hl >> 4) * 64 + (hl & 15);
  float A = 1.f, Bv = 0.f;
#pragma unroll
  for (int i = 0; i < 4; i++)
#pragma unroll
    for (int p = 0; p < 4; p++) {
      h8v g = cab[base + i * 256 + p * 16];
#pragma unroll
      for (int q = 0; q < 4; q++) {
        float a = (float)g[q], b = (float)g[4 + q];
        A *= a;
        Bv = fmaf(a, Bv, b);
      }
    }
  cA[(size_t)R * Hn + h] = A;
  cB[(size_t)R * Hn + h] = Bv;
}

// S2: serial scan over 64 chunk summaries per (b,h) -> h_start per chunk
__global__ __launch_bounds__(256) void scan_heads(
    const float* __restrict__ cA, const float* __restrict__ cB,
    const float* __restrict__ h0p, float* __restrict__ hst) {
  int gid = blockIdx.x * 256 + threadIdx.x;   // 4096 = B*H
  int b = gid >> 9, h = gid & 511;
  float hr = h0p[(size_t)b * Hn + h];
#pragma unroll 8
  for (int c = 0; c < NC; c++) {
    size_t o = (size_t)(b * NC + c) * Hn + h;
    hst[o] = hr;
    hr = fmaf(cA[o], hr, cB[o]);
  }
}

// S3: replay each chunk from its h_start, write fp32 outputs (B,T,H)
__global__ __launch_bounds__(256) void scan_apply(
    const h8v* __restrict__ cab, const float* __restrict__ hst,
    float* __restrict__ out) {
  int h = blockIdx.y * 256 + threadIdx.x;
  int R = blockIdx.x;
  int hl = h & 63, Cc = h >> 6;
  size_t base = (size_t)(R * 8 + Cc) * 1024 + (size_t)(hl >> 4) * 64 + (hl & 15);
  float hr = hst[(size_t)R * Hn + h];
  size_t ob = (size_t)R * 64 * Hn + h;
#pragma unroll
  for (int i = 0; i < 4; i++)
#pragma unroll
    for (int p = 0; p < 4; p++) {
      h8v g = cab[base + i * 256 + p * 16];
#pragma unroll
      for (int q = 0; q < 4; q++) {
        hr = fmaf((float)g[q], hr, (float)g[4 + q]);
        out[ob + (size_t)(i * 16 + p * 4 + q) * Hn] = hr;
      }
    }
}

extern "C" void kernel_launch(void* const* d_in, const int* in_sizes, int n_in,
                              void* d_out, int out_size, void* d_ws, size_t ws_size,
                              hipStream_t stream) {
  const float* X   = (const float*)d_in[0];
  const float* h0p = (const float*)d_in[1];
  const float* Wz  = (const float*)d_in[2];
  const float* bz  = (const float*)d_in[3];
  const float* Wh  = (const float*)d_in[4];
  const float* bh  = (const float*)d_in[5];
  float* out = (float*)d_out;

  char* ws = (char*)d_ws;
  ushort_t* Xb  = (ushort_t*)ws;                                  // 33.6 MB
  ushort_t* Wzb = Xb + (size_t)Mn * Dn;                           // 0.5 MB
  ushort_t* Whb = Wzb + (size_t)Hn * Dn;                          // 0.5 MB
  h8v* cab      = (h8v*)(Whb + (size_t)Hn * Dn);                  // 67.1 MB
  // cab = 2*Mn*Hn halves = Mn*Hn/4 granules of 16B
  float* cA     = (float*)(cab + (size_t)Mn * Hn / 4);            // 1 MB
  float* cB     = cA + (size_t)Bn * NC * Hn;                      // 1 MB
  float* hst    = cB + (size_t)Bn * NC * Hn;                      // 1 MB

  convert_all<<<dim3(4224), 256, 0, stream>>>(X, Wz, Wh, Xb, Wzb, Whb);

  gemm_act<<<dim3(Mn / BM, Hn / BHt), 256, 0, stream>>>(Xb, Wzb, Whb, bz, bh, cab);

  scan_chunk<<<dim3(Mn / 64, Hn / 256), 256, 0, stream>>>(cab, cA, cB);
  scan_heads<<<dim3(Bn * Hn / 256), 256, 0, stream>>>(cA, cB, h0p, hst);
  scan_apply<<<dim3(Mn / 64, Hn / 256), 256, 0, stream>>>(cab, hst, out);
}

// Round 5
// 105.726 us; speedup vs baseline: 2.1793x; 1.0524x over previous
//
#include <hip/hip_runtime.h>

constexpr int Bn = 8, Tn = 4096, Dn = 512, Hn = 512;
constexpr int Mn = Bn * Tn;            // 32768 rows
constexpr int BM = 128, BHt = 128, BK = 32;
constexpr int NKT = Dn / BK;           // 16 k-tiles
constexpr int CH = 64, NC = Tn / CH;   // 64 chunks of 64 steps

typedef __attribute__((ext_vector_type(8))) short s8v;       // 8 bf16
typedef __attribute__((ext_vector_type(4))) float f4v;       // MFMA acc
typedef __attribute__((ext_vector_type(8))) _Float16 h8v;    // 16B granule: a[0..3], b[0..3]
typedef unsigned short ushort_t;

__device__ __forceinline__ short f2bf(float f) {
  unsigned u = __float_as_uint(f);
  u = (u + 0x7fffu + ((u >> 16) & 1u)) >> 16;   // RNE
  return (short)u;
}

// fp32 [rows][512] -> bf16 tiles of 128 rows x 32 k in MFMA-fragment order.
// Tile t = rt*16 + kt; within tile, 16B chunk c = (r>>4)*64 + k8*16 + (r&15)
// holds row r's elements [k8*8 .. +8]. A wave's fragment (64 consecutive
// chunks) is 1KB contiguous -> direct coalesced global_load_dwordx4.
// Blocks [0,4096) = X, [4096,4160) = Wz, [4160,4224) = Wh.
__global__ __launch_bounds__(256) void convert_all(
    const float* __restrict__ X, const float* __restrict__ Wz,
    const float* __restrict__ Wh, ushort_t* __restrict__ Xb,
    ushort_t* __restrict__ Wzb, ushort_t* __restrict__ Whb) {
  int bx = blockIdx.x, tid = threadIdx.x;
  const float* src;
  ushort_t* dst;
  int lb;
  if (bx < 4096)      { src = X;  dst = Xb;  lb = bx; }
  else if (bx < 4160) { src = Wz; dst = Wzb; lb = bx - 4096; }
  else                { src = Wh; dst = Whb; lb = bx - 4160; }
  const float* tsrc = src + ((size_t)(lb >> 4) * 128) * Dn + (lb & 15) * BK;
#pragma unroll
  for (int p = 0; p < 2; p++) {
    int idx = tid + p * 256;
    int r = idx >> 2, k8 = idx & 3;
    const float4* sv = reinterpret_cast<const float4*>(tsrc + (size_t)r * Dn + k8 * 8);
    float4 f0 = sv[0], f1 = sv[1];
    s8v v;
    v[0] = f2bf(f0.x); v[1] = f2bf(f0.y); v[2] = f2bf(f0.z); v[3] = f2bf(f0.w);
    v[4] = f2bf(f1.x); v[5] = f2bf(f1.y); v[6] = f2bf(f1.z); v[7] = f2bf(f1.w);
    int c = (r >> 4) * 64 + k8 * 16 + (r & 15);
    *reinterpret_cast<s8v*>(&dst[((size_t)lb * 512 + c) * 8]) = v;
  }
}

// Dual bf16 GEMM + activation epilogue. ZERO LDS, ZERO barriers:
// fragments are loaded straight from the pre-swizzled global layout into
// VGPRs (16B/lane coalesced); compiler free to pipeline loads across the
// whole K-loop. 2x2 waves, 64x64 per wave per matrix.
// Output: packed fp16 granules, wave-tile layout:
//   granule chunk = (R*8+Cc)*1024 + (i*4+j)*64 + lane holding {a,b} for
//   t_loc = i*16 + (lane>>4)*4 + q, h_loc = j*16 + (lane&15); R=m/64, Cc=h/64.
__global__ __launch_bounds__(256, 2) void gemm_act(
    const ushort_t* __restrict__ Xb, const ushort_t* __restrict__ Wzb,
    const ushort_t* __restrict__ Whb,
    const float* __restrict__ bzp, const float* __restrict__ bhp,
    h8v* __restrict__ cab) {
  int tid = threadIdx.x, lane = tid & 63, wid = tid >> 6;
  int wr = wid >> 1, wc = wid & 1;
  int bm = blockIdx.x, bhb = blockIdx.y;

  // per-wave fragment base pointers (lane-resolved, 16B granules)
  const s8v* xs = reinterpret_cast<const s8v*>(Xb) + (size_t)bm * NKT * 512 + (wr * 4) * 64 + lane;
  const s8v* zs = reinterpret_cast<const s8v*>(Wzb) + (size_t)bhb * NKT * 512 + (wc * 4) * 64 + lane;
  const s8v* hs = reinterpret_cast<const s8v*>(Whb) + (size_t)bhb * NKT * 512 + (wc * 4) * 64 + lane;

  f4v accz[4][4], acch[4][4];
#pragma unroll
  for (int i = 0; i < 4; i++)
#pragma unroll
    for (int j = 0; j < 4; j++) {
      accz[i][j] = (f4v){0.f, 0.f, 0.f, 0.f};
      acch[i][j] = (f4v){0.f, 0.f, 0.f, 0.f};
    }

#pragma unroll 2
  for (int ks = 0; ks < NKT; ks++) {
    s8v af[4], bzf[4], bhf[4];
#pragma unroll
    for (int i = 0; i < 4; i++) af[i] = xs[ks * 512 + i * 64];
#pragma unroll
    for (int j = 0; j < 4; j++) {
      bzf[j] = zs[ks * 512 + j * 64];
      bhf[j] = hs[ks * 512 + j * 64];
    }
#pragma unroll
    for (int i = 0; i < 4; i++)
#pragma unroll
      for (int j = 0; j < 4; j++) {
        accz[i][j] = __builtin_amdgcn_mfma_f32_16x16x32_bf16(af[i], bzf[j], accz[i][j], 0, 0, 0);
        acch[i][j] = __builtin_amdgcn_mfma_f32_16x16x32_bf16(af[i], bhf[j], acch[i][j], 0, 0, 0);
      }
  }

  // epilogue: C/D layout col=lane&15, row=(lane>>4)*4+q  [m89/m91]
  int R = bm * 2 + wr, Cc = bhb * 2 + wc;
  size_t base = (size_t)(R * 8 + Cc) * 1024;
  float bzv[4], bhv[4];
#pragma unroll
  for (int j = 0; j < 4; j++) {
    int h = bhb * BHt + wc * 64 + j * 16 + (lane & 15);
    bzv[j] = bzp[h];
    bhv[j] = bhp[h];
  }
#pragma unroll
  for (int i = 0; i < 4; i++)
#pragma unroll
    for (int j = 0; j < 4; j++) {
      h8v g;
#pragma unroll
      for (int q = 0; q < 4; q++) {
        float z = 1.f / (1.f + __expf(-(accz[i][j][q] + bzv[j])));
        float e = __expf(2.f * (acch[i][j][q] + bhv[j]));
        float th = 1.f - 2.f / (e + 1.f);
        g[q] = (_Float16)(1.f - z);        // a_t
        g[4 + q] = (_Float16)(z * th);     // b_t
      }
      cab[base + (size_t)((i * 4 + j) * 64 + lane)] = g;
    }
}

// S1: per (R = b*64+c, h) compose the 64-step affine transform -> (A, B)
__global__ __launch_bounds__(256) void scan_chunk(
    const h8v* __restrict__ cab, float* __restrict__ cA, float* __restrict__ cB) {
  int h = blockIdx.y * 256 + threadIdx.x;
  int R = blockIdx.x;
  int hl = h & 63, Cc = h >> 6;
  size_t base = (size_t)(R * 8 + Cc) * 1024 + (size_t)(hl >> 4) * 64 + (hl & 15);
  float A = 1.f, Bv = 0.f;
#pragma unroll
  for (int i = 0; i < 4; i++)
#pragma unroll
    for (int p = 0; p < 4; p++) {
      h8v g = cab[base + i * 256 + p * 16];
#pragma unroll
      for (int q = 0; q < 4; q++) {
        float a = (float)g[q], b = (float)g[4 + q];
        A *= a;
        Bv = fmaf(a, Bv, b);
      }
    }
  cA[(size_t)R * Hn + h] = A;
  cB[(size_t)R * Hn + h] = Bv;
}

// S2: serial scan over 64 chunk summaries per (b,h) -> h_start per chunk
__global__ __launch_bounds__(256) void scan_heads(
    const float* __restrict__ cA, const float* __restrict__ cB,
    const float* __restrict__ h0p, float* __restrict__ hst) {
  int gid = blockIdx.x * 256 + threadIdx.x;   // 4096 = B*H
  int b = gid >> 9, h = gid & 511;
  float hr = h0p[(size_t)b * Hn + h];
#pragma unroll 8
  for (int c = 0; c < NC; c++) {
    size_t o = (size_t)(b * NC + c) * Hn + h;
    hst[o] = hr;
    hr = fmaf(cA[o], hr, cB[o]);
  }
}

// S3: replay each chunk from its h_start, write fp32 outputs (B,T,H)
__global__ __launch_bounds__(256) void scan_apply(
    const h8v* __restrict__ cab, const float* __restrict__ hst,
    float* __restrict__ out) {
  int h = blockIdx.y * 256 + threadIdx.x;
  int R = blockIdx.x;
  int hl = h & 63, Cc = h >> 6;
  size_t base = (size_t)(R * 8 + Cc) * 1024 + (size_t)(hl >> 4) * 64 + (hl & 15);
  float hr = hst[(size_t)R * Hn + h];
  size_t ob = (size_t)R * 64 * Hn + h;
#pragma unroll
  for (int i = 0; i < 4; i++)
#pragma unroll
    for (int p = 0; p < 4; p++) {
      h8v g = cab[base + i * 256 + p * 16];
#pragma unroll
      for (int q = 0; q < 4; q++) {
        hr = fmaf((float)g[q], hr, (float)g[4 + q]);
        out[ob + (size_t)(i * 16 + p * 4 + q) * Hn] = hr;
      }
    }
}

extern "C" void kernel_launch(void* const* d_in, const int* in_sizes, int n_in,
                              void* d_out, int out_size, void* d_ws, size_t ws_size,
                              hipStream_t stream) {
  const float* X   = (const float*)d_in[0];
  const float* h0p = (const float*)d_in[1];
  const float* Wz  = (const float*)d_in[2];
  const float* bz  = (const float*)d_in[3];
  const float* Wh  = (const float*)d_in[4];
  const float* bh  = (const float*)d_in[5];
  float* out = (float*)d_out;

  char* ws = (char*)d_ws;
  ushort_t* Xb  = (ushort_t*)ws;                                  // 33.6 MB
  ushort_t* Wzb = Xb + (size_t)Mn * Dn;                           // 0.5 MB
  ushort_t* Whb = Wzb + (size_t)Hn * Dn;                          // 0.5 MB
  h8v* cab      = (h8v*)(Whb + (size_t)Hn * Dn);                  // 67.1 MB
  // cab = 2*Mn*Hn halves = Mn*Hn/4 granules of 16B
  float* cA     = (float*)(cab + (size_t)Mn * Hn / 4);            // 1 MB
  float* cB     = cA + (size_t)Bn * NC * Hn;                      // 1 MB
  float* hst    = cB + (size_t)Bn * NC * Hn;                      // 1 MB

  convert_all<<<dim3(4224), 256, 0, stream>>>(X, Wz, Wh, Xb, Wzb, Whb);

  gemm_act<<<dim3(Mn / BM, Hn / BHt), 256, 0, stream>>>(Xb, Wzb, Whb, bz, bh, cab);

  scan_chunk<<<dim3(Mn / 64, Hn / 256), 256, 0, stream>>>(cab, cA, cB);
  scan_heads<<<dim3(Bn * Hn / 256), 256, 0, stream>>>(cA, cB, h0p, hst);
  scan_apply<<<dim3(Mn / 64, Hn / 256), 256, 0, stream>>>(cab, hst, out);
}

// Round 6
// 99.329 us; speedup vs baseline: 2.3197x; 1.0644x over previous
//
#include <hip/hip_runtime.h>

constexpr int Bn = 8, Tn = 4096, Dn = 512, Hn = 512;
constexpr int Mn = Bn * Tn;            // 32768 rows
constexpr int BM = 128, BHt = 128, BK = 32;
constexpr int NKT = Dn / BK;           // 16 k-tiles
constexpr int CH = 64, NC = Tn / CH;   // 64 chunks of 64 steps

typedef __attribute__((ext_vector_type(8))) short s8v;       // 8 bf16
typedef __attribute__((ext_vector_type(4))) float f4v;       // MFMA acc
typedef __attribute__((ext_vector_type(8))) _Float16 h8v;    // 16B granule: a[0..3], b[0..3]
typedef unsigned short ushort_t;

__device__ __forceinline__ short f2bf(float f) {
  unsigned u = __float_as_uint(f);
  u = (u + 0x7fffu + ((u >> 16) & 1u)) >> 16;   // RNE
  return (short)u;
}

// fp32 [rows][512] -> bf16 tiles of 128 rows x 32 k in MFMA-fragment order.
// Tile t = rt*16 + kt; within tile, 16B chunk c = (r>>4)*64 + k8*16 + (r&15)
// holds row r's elements [k8*8 .. +8]. A wave's fragment (64 consecutive
// chunks) is 1KB contiguous -> direct coalesced global_load_dwordx4.
// Blocks [0,4096) = X, [4096,4160) = Wz, [4160,4224) = Wh.
__global__ __launch_bounds__(256) void convert_all(
    const float* __restrict__ X, const float* __restrict__ Wz,
    const float* __restrict__ Wh, ushort_t* __restrict__ Xb,
    ushort_t* __restrict__ Wzb, ushort_t* __restrict__ Whb) {
  int bx = blockIdx.x, tid = threadIdx.x;
  const float* src;
  ushort_t* dst;
  int lb;
  if (bx < 4096)      { src = X;  dst = Xb;  lb = bx; }
  else if (bx < 4160) { src = Wz; dst = Wzb; lb = bx - 4096; }
  else                { src = Wh; dst = Whb; lb = bx - 4160; }
  const float* tsrc = src + ((size_t)(lb >> 4) * 128) * Dn + (lb & 15) * BK;
#pragma unroll
  for (int p = 0; p < 2; p++) {
    int idx = tid + p * 256;
    int r = idx >> 2, k8 = idx & 3;
    const float4* sv = reinterpret_cast<const float4*>(tsrc + (size_t)r * Dn + k8 * 8);
    float4 f0 = sv[0], f1 = sv[1];
    s8v v;
    v[0] = f2bf(f0.x); v[1] = f2bf(f0.y); v[2] = f2bf(f0.z); v[3] = f2bf(f0.w);
    v[4] = f2bf(f1.x); v[5] = f2bf(f1.y); v[6] = f2bf(f1.z); v[7] = f2bf(f1.w);
    int c = (r >> 4) * 64 + k8 * 16 + (r & 15);
    *reinterpret_cast<s8v*>(&dst[((size_t)lb * 512 + c) * 8]) = v;
  }
}

// Dual bf16 GEMM + activation + FUSED chunk-summary epilogue.
// Zero LDS / zero barriers; fragments straight from pre-swizzled global.
// Partial register double-buffer: af+bzf 2-deep (stays under 256-reg cliff
// with 128 AGPR accs); bhf single-buffered, reloaded right after acch use.
// Granule layout: chunk = (R*8+Cc)*1024 + (i*4+j)*64 + lane holding {a,b} for
// t_loc = i*16 + (lane>>4)*4 + q, h_loc = j*16 + (lane&15); R=m/64, Cc=h/64.
__global__ __launch_bounds__(256, 2) void gemm_act(
    const ushort_t* __restrict__ Xb, const ushort_t* __restrict__ Wzb,
    const ushort_t* __restrict__ Whb,
    const float* __restrict__ bzp, const float* __restrict__ bhp,
    h8v* __restrict__ cab, float* __restrict__ cA, float* __restrict__ cB) {
  int tid = threadIdx.x, lane = tid & 63, wid = tid >> 6;
  int wr = wid >> 1, wc = wid & 1;
  int bm = blockIdx.x, bhb = blockIdx.y;

  const s8v* xs = reinterpret_cast<const s8v*>(Xb) + (size_t)bm * NKT * 512 + (wr * 4) * 64 + lane;
  const s8v* zs = reinterpret_cast<const s8v*>(Wzb) + (size_t)bhb * NKT * 512 + (wc * 4) * 64 + lane;
  const s8v* hs = reinterpret_cast<const s8v*>(Whb) + (size_t)bhb * NKT * 512 + (wc * 4) * 64 + lane;

  f4v accz[4][4], acch[4][4];
#pragma unroll
  for (int i = 0; i < 4; i++)
#pragma unroll
    for (int j = 0; j < 4; j++) {
      accz[i][j] = (f4v){0.f, 0.f, 0.f, 0.f};
      acch[i][j] = (f4v){0.f, 0.f, 0.f, 0.f};
    }

  s8v afA[4], bzA[4], afB[4], bzB[4], bhf[4];
#pragma unroll
  for (int i = 0; i < 4; i++) afA[i] = xs[i * 64];
#pragma unroll
  for (int j = 0; j < 4; j++) bzA[j] = zs[j * 64];
#pragma unroll
  for (int j = 0; j < 4; j++) bhf[j] = hs[j * 64];

#pragma unroll
  for (int ks = 0; ks < NKT; ks += 2) {
    // prefetch ks+1 into B (af, bz)
#pragma unroll
    for (int i = 0; i < 4; i++) afB[i] = xs[(ks + 1) * 512 + i * 64];
#pragma unroll
    for (int j = 0; j < 4; j++) bzB[j] = zs[(ks + 1) * 512 + j * 64];
    // compute ks from A (+ current bhf)
#pragma unroll
    for (int i = 0; i < 4; i++)
#pragma unroll
      for (int j = 0; j < 4; j++)
        accz[i][j] = __builtin_amdgcn_mfma_f32_16x16x32_bf16(afA[i], bzA[j], accz[i][j], 0, 0, 0);
#pragma unroll
    for (int i = 0; i < 4; i++)
#pragma unroll
      for (int j = 0; j < 4; j++)
        acch[i][j] = __builtin_amdgcn_mfma_f32_16x16x32_bf16(afA[i], bhf[j], acch[i][j], 0, 0, 0);
#pragma unroll
    for (int j = 0; j < 4; j++) bhf[j] = hs[(ks + 1) * 512 + j * 64];
    // prefetch ks+2 into A
    if (ks + 2 < NKT) {
#pragma unroll
      for (int i = 0; i < 4; i++) afA[i] = xs[(ks + 2) * 512 + i * 64];
#pragma unroll
      for (int j = 0; j < 4; j++) bzA[j] = zs[(ks + 2) * 512 + j * 64];
    }
    // compute ks+1 from B (+ reloaded bhf)
#pragma unroll
    for (int i = 0; i < 4; i++)
#pragma unroll
      for (int j = 0; j < 4; j++)
        accz[i][j] = __builtin_amdgcn_mfma_f32_16x16x32_bf16(afB[i], bzB[j], accz[i][j], 0, 0, 0);
#pragma unroll
    for (int i = 0; i < 4; i++)
#pragma unroll
      for (int j = 0; j < 4; j++)
        acch[i][j] = __builtin_amdgcn_mfma_f32_16x16x32_bf16(afB[i], bhf[j], acch[i][j], 0, 0, 0);
    if (ks + 2 < NKT) {
#pragma unroll
      for (int j = 0; j < 4; j++) bhf[j] = hs[(ks + 2) * 512 + j * 64];
    }
  }

  // ---- epilogue: C/D layout col=lane&15, row=(lane>>4)*4+q  [m89/m91] ----
  int R = bm * 2 + wr, Cc = bhb * 2 + wc;
  size_t base = (size_t)(R * 8 + Cc) * 1024;
  float bzv[4], bhv[4];
#pragma unroll
  for (int j = 0; j < 4; j++) {
    int h = bhb * BHt + wc * 64 + j * 16 + (lane & 15);
    bzv[j] = bzp[h];
    bhv[j] = bhp[h];
  }
  float QA[4][4], QB[4][4];   // per-(i,j) 4-t composites from ROUNDED fp16 a,b
#pragma unroll
  for (int i = 0; i < 4; i++)
#pragma unroll
    for (int j = 0; j < 4; j++) {
      h8v g;
      float Pa = 1.f, Pb = 0.f;
#pragma unroll
      for (int q = 0; q < 4; q++) {
        float z = 1.f / (1.f + __expf(-(accz[i][j][q] + bzv[j])));
        float e = __expf(2.f * (acch[i][j][q] + bhv[j]));
        float th = 1.f - 2.f / (e + 1.f);
        g[q] = (_Float16)(1.f - z);        // a_t
        g[4 + q] = (_Float16)(z * th);     // b_t
        float a = (float)g[q], b = (float)g[4 + q];
        Pa = a * Pa;                        // t ascending within lane (q)
        Pb = a * Pb + b;
      }
      cab[base + (size_t)((i * 4 + j) * 64 + lane)] = g;
      QA[i][j] = Pa;
      QB[i][j] = Pb;
    }

  // fused chunk summary: compose over lane-groups g=(lane>>4) then i, per j.
  // order: t = i*16 + g*4 + q  ->  segments (i,g) lexicographic.
#pragma unroll
  for (int j = 0; j < 4; j++) {
    float A = 1.f, Bv = 0.f;
#pragma unroll
    for (int i = 0; i < 4; i++) {
      float a = QA[i][j], b = QB[i][j];
      float ap = __shfl_xor(a, 16), bp = __shfl_xor(b, 16);
      bool hi = (lane & 16) != 0;
      float af_ = hi ? ap : a, bf_ = hi ? bp : b;   // earlier segment
      float as_ = hi ? a : ap, bs_ = hi ? b : bp;   // later segment
      a = as_ * af_; b = as_ * bf_ + bs_;
      ap = __shfl_xor(a, 32); bp = __shfl_xor(b, 32);
      bool hi2 = (lane & 32) != 0;
      af_ = hi2 ? ap : a; bf_ = hi2 ? bp : b;
      as_ = hi2 ? a : ap; bs_ = hi2 ? b : bp;
      a = as_ * af_; b = as_ * bf_ + bs_;
      // (a,b) = composite over t in [i*16, (i+1)*16); apply after prefix
      Bv = a * Bv + b;
      A = a * A;
    }
    if (lane < 16) {
      int h = bhb * BHt + wc * 64 + j * 16 + lane;
      cA[(size_t)R * Hn + h] = A;
      cB[(size_t)R * Hn + h] = Bv;
    }
  }
}

// S2: serial scan over 64 chunk summaries per (b,h) -> h_start per chunk
__global__ __launch_bounds__(256) void scan_heads(
    const float* __restrict__ cA, const float* __restrict__ cB,
    const float* __restrict__ h0p, float* __restrict__ hst) {
  int gid = blockIdx.x * 256 + threadIdx.x;   // 4096 = B*H
  int b = gid >> 9, h = gid & 511;
  float hr = h0p[(size_t)b * Hn + h];
#pragma unroll 8
  for (int c = 0; c < NC; c++) {
    size_t o = (size_t)(b * NC + c) * Hn + h;
    hst[o] = hr;
    hr = fmaf(cA[o], hr, cB[o]);
  }
}

// S3: replay each chunk from its h_start, write fp32 outputs (B,T,H)
__global__ __launch_bounds__(256) void scan_apply(
    const h8v* __restrict__ cab, const float* __restrict__ hst,
    float* __restrict__ out) {
  int h = blockIdx.y * 256 + threadIdx.x;
  int R = blockIdx.x;
  int hl = h & 63, Cc = h >> 6;
  size_t base = (size_t)(R * 8 + Cc) * 1024 + (size_t)(hl >> 4) * 64 + (hl & 15);
  float hr = hst[(size_t)R * Hn + h];
  size_t ob = (size_t)R * 64 * Hn + h;
#pragma unroll
  for (int i = 0; i < 4; i++)
#pragma unroll
    for (int p = 0; p < 4; p++) {
      h8v g = cab[base + i * 256 + p * 16];
#pragma unroll
      for (int q = 0; q < 4; q++) {
        hr = fmaf((float)g[q], hr, (float)g[4 + q]);
        out[ob + (size_t)(i * 16 + p * 4 + q) * Hn] = hr;
      }
    }
}

extern "C" void kernel_launch(void* const* d_in, const int* in_sizes, int n_in,
                              void* d_out, int out_size, void* d_ws, size_t ws_size,
                              hipStream_t stream) {
  const float* X   = (const float*)d_in[0];
  const float* h0p = (const float*)d_in[1];
  const float* Wz  = (const float*)d_in[2];
  const float* bz  = (const float*)d_in[3];
  const float* Wh  = (const float*)d_in[4];
  const float* bh  = (const float*)d_in[5];
  float* out = (float*)d_out;

  char* ws = (char*)d_ws;
  ushort_t* Xb  = (ushort_t*)ws;                                  // 33.6 MB
  ushort_t* Wzb = Xb + (size_t)Mn * Dn;                           // 0.5 MB
  ushort_t* Whb = Wzb + (size_t)Hn * Dn;                          // 0.5 MB
  h8v* cab      = (h8v*)(Whb + (size_t)Hn * Dn);                  // 67.1 MB
  // cab = 2*Mn*Hn halves = Mn*Hn/4 granules of 16B
  float* cA     = (float*)(cab + (size_t)Mn * Hn / 4);            // 1 MB
  float* cB     = cA + (size_t)Bn * NC * Hn;                      // 1 MB
  float* hst    = cB + (size_t)Bn * NC * Hn;                      // 1 MB

  convert_all<<<dim3(4224), 256, 0, stream>>>(X, Wz, Wh, Xb, Wzb, Whb);

  gemm_act<<<dim3(Mn / BM, Hn / BHt), 256, 0, stream>>>(Xb, Wzb, Whb, bz, bh, cab, cA, cB);

  scan_heads<<<dim3(Bn * Hn / 256), 256, 0, stream>>>(cA, cB, h0p, hst);
  scan_apply<<<dim3(Mn / 64, Hn / 256), 256, 0, stream>>>(cab, hst, out);
}